// Round 5
// baseline (406.760 us; speedup 1.0000x reference)
//
#include <hip/hip_runtime.h>

typedef unsigned short u16;
typedef unsigned int u32;
typedef __bf16 bf16x8 __attribute__((ext_vector_type(8)));
typedef float f32x4 __attribute__((ext_vector_type(4)));
typedef u16 u16x8 __attribute__((ext_vector_type(8)));

#define T_SEQ 4096
#define E_DIM 512
#define H_HEADS 8
#define FF_DIM 2048
#define BATCH 2
#define MROWS (BATCH * T_SEQ) /* 8192 */

__device__ __forceinline__ float bf2f(u16 u) {
  union { u32 i; float f; } w; w.i = ((u32)u) << 16; return w.f;
}
__device__ __forceinline__ u16 f2bf(float f) {
  union { float f; u32 i; } w; w.f = f;
  u32 r = w.i + 0x7FFFu + ((w.i >> 16) & 1u);
  return (u16)(r >> 16);
}
__device__ __forceinline__ void gload_lds16(const void* g, void* l) {
  __builtin_amdgcn_global_load_lds(
      (const __attribute__((address_space(1))) void*)g,
      (__attribute__((address_space(3))) void*)l, 16, 0, 0);
}

// ---------------------------------------------------------------------------
// Weight convert+transpose: out[n][k] = (bf16) in[k][n]
// ---------------------------------------------------------------------------
__global__ __launch_bounds__(256) void wconv_kernel(
    const float* __restrict__ Wq, const float* __restrict__ Wk,
    const float* __restrict__ Wv, const float* __restrict__ Wo,
    const float* __restrict__ W1, const float* __restrict__ W2,
    u16* __restrict__ wqkv_t, u16* __restrict__ wo_t,
    u16* __restrict__ w1_t, u16* __restrict__ w2_t) {
  const int z = blockIdx.y;
  const int l = z / 6, ty = z % 6;
  const float* in; u16* op; int K, N;
  const size_t EE = (size_t)E_DIM * E_DIM;
  const size_t EF = (size_t)E_DIM * FF_DIM;
  switch (ty) {
    case 0: in = Wq + l * EE; op = wqkv_t + l * 3 * EE;          K = E_DIM;  N = E_DIM;  break;
    case 1: in = Wk + l * EE; op = wqkv_t + l * 3 * EE + EE;     K = E_DIM;  N = E_DIM;  break;
    case 2: in = Wv + l * EE; op = wqkv_t + l * 3 * EE + 2 * EE; K = E_DIM;  N = E_DIM;  break;
    case 3: in = Wo + l * EE; op = wo_t + l * EE;                K = E_DIM;  N = E_DIM;  break;
    case 4: in = W1 + l * EF; op = w1_t + l * EF;                K = E_DIM;  N = FF_DIM; break;
    default:in = W2 + l * EF; op = w2_t + l * EF;                K = FF_DIM; N = E_DIM;  break;
  }
  const int nn = N >> 5;
  const int ntile = (K >> 5) * nn;
  const int tile = blockIdx.x;
  if (tile >= ntile) return;
  const int tk = tile / nn, tn = tile % nn;
  __shared__ float tl[32][33];
  const int tx = threadIdx.x & 31, tr = threadIdx.x >> 5;
#pragma unroll
  for (int i = 0; i < 4; i++)
    tl[tr + i * 8][tx] = in[(size_t)(tk * 32 + tr + i * 8) * N + tn * 32 + tx];
  __syncthreads();
#pragma unroll
  for (int i = 0; i < 4; i++)
    op[(size_t)(tn * 32 + tr + i * 8) * K + tk * 32 + tx] = f2bf(tl[tx][tr + i * 8]);
}

// ---------------------------------------------------------------------------
// Embedding
// ---------------------------------------------------------------------------
__global__ __launch_bounds__(256) void embed_kernel(
    const int* __restrict__ tokens, const float* __restrict__ tok_emb,
    const float* __restrict__ pos_emb, float* __restrict__ x) {
  const int idx = blockIdx.x * 256 + threadIdx.x;   // over 8192*128
  const int rowi = idx >> 7, c4 = (idx & 127) * 4;
  const int t = rowi & (T_SEQ - 1);
  const int tok = tokens[rowi];
  float4 e = *(const float4*)(tok_emb + (size_t)tok * E_DIM + c4);
  float4 p = *(const float4*)(pos_emb + (size_t)t * E_DIM + c4);
  e.x += p.x; e.y += p.y; e.z += p.z; e.w += p.w;
  *(float4*)(x + (size_t)rowi * E_DIM + c4) = e;
}

// ---------------------------------------------------------------------------
// LayerNorm: one wave per row of 512; fp32 in, bf16 out.
// ---------------------------------------------------------------------------
__global__ __launch_bounds__(256) void ln_kernel(
    const float* __restrict__ x, const float* __restrict__ gam,
    const float* __restrict__ bet, u16* __restrict__ out) {
  const int row = blockIdx.x * 4 + (threadIdx.x >> 6);
  const int lane = threadIdx.x & 63;
  const float* xr = x + (size_t)row * E_DIM + lane * 8;
  float4 v0 = *(const float4*)xr;
  float4 v1 = *(const float4*)(xr + 4);
  float s  = v0.x + v0.y + v0.z + v0.w + v1.x + v1.y + v1.z + v1.w;
  float s2 = v0.x * v0.x + v0.y * v0.y + v0.z * v0.z + v0.w * v0.w +
             v1.x * v1.x + v1.y * v1.y + v1.z * v1.z + v1.w * v1.w;
#pragma unroll
  for (int o = 32; o; o >>= 1) { s += __shfl_xor(s, o); s2 += __shfl_xor(s2, o); }
  const float mean = s * (1.f / E_DIM);
  const float var = s2 * (1.f / E_DIM) - mean * mean;
  const float inv = rsqrtf(var + 1e-5f);
  float4 g0 = *(const float4*)(gam + lane * 8);
  float4 g1 = *(const float4*)(gam + lane * 8 + 4);
  float4 b0 = *(const float4*)(bet + lane * 8);
  float4 b1 = *(const float4*)(bet + lane * 8 + 4);
  u16x8 o8;
  o8[0] = f2bf((v0.x - mean) * inv * g0.x + b0.x);
  o8[1] = f2bf((v0.y - mean) * inv * g0.y + b0.y);
  o8[2] = f2bf((v0.z - mean) * inv * g0.z + b0.z);
  o8[3] = f2bf((v0.w - mean) * inv * g0.w + b0.w);
  o8[4] = f2bf((v1.x - mean) * inv * g1.x + b1.x);
  o8[5] = f2bf((v1.y - mean) * inv * g1.y + b1.y);
  o8[6] = f2bf((v1.z - mean) * inv * g1.z + b1.z);
  o8[7] = f2bf((v1.w - mean) * inv * g1.w + b1.w);
  *(u16x8*)(out + (size_t)row * E_DIM + lane * 8) = o8;
}

// ---------------------------------------------------------------------------
// NT GEMM: C[M,N] = A[M,K] @ Bt[N,K]^T, bf16 in, fp32 acc.
// 3-deep LDS rotation + counted vmcnt (T4): stage(t+2) issued each iter,
// s_waitcnt vmcnt(6) + raw s_barrier per K-step -> next tile's loads stay
// in flight across the barrier (never drain to 0 in the main loop).
// T2 both-sides XOR swizzle, T1 XCD swizzle, T5 setprio.
// Tile 128x64, BK=64, 4 waves (2x2). LDS 3*(128+64)*64*2B = 72 KB
// -> 2 blocks/CU. grid: 1-D, gx = N/64 tiles.
// Race-safety: ds_reads of buf t are consumed (lgkmcnt'd) before the
// barrier; overwrite of buf[(t+2)%3] is issued >=1 barrier after its last
// read; per-wave vmcnt + barrier join covers cross-wave staging;
// sched_barrier(0) pins ds_reads below the barrier.
// ---------------------------------------------------------------------------
template <int BM, int BN, bool BIAS, bool RELU, bool RESID, bool OUTBF>
__global__ __launch_bounds__(256) void gemm_nt(
    const u16* __restrict__ A, const u16* __restrict__ Bt,
    const float* __restrict__ bias, const float* __restrict__ resid,
    void* __restrict__ outp, int K, int N, int gx) {
  constexpr int BK = 64;
  constexpr int FM = BM / 32, FN = BN / 32;
  __shared__ __align__(16) u16 As[3][BM * BK];
  __shared__ __align__(16) u16 Bs[3][BN * BK];
  const int tid = threadIdx.x;
  const int wave = tid >> 6, lane = tid & 63;

  const int cpx = gridDim.x >> 3;
  const int bid = blockIdx.x;
  const int sw = (bid & 7) * cpx + (bid >> 3);
  const int bx = sw % gx, by = sw / gx;

  const int m0 = by * BM, n0 = bx * BN;
  const int wr = wave >> 1, wc = wave & 1;
  const int r = lane & 15, g = lane >> 4;

  const int srow = lane >> 3;
  const int scol = (lane & 7) ^ srow;

  f32x4 acc[FM][FN];
#pragma unroll
  for (int i = 0; i < FM; i++)
#pragma unroll
    for (int j = 0; j < FN; j++) acc[i][j] = (f32x4){0.f, 0.f, 0.f, 0.f};

  constexpr int ASEG = BM / 8, BSEG = BN / 8;   // 16, 8
  // per-thread loads per K-step: ASEG/4 + BSEG/4 = 4 + 2 = 6  -> vmcnt(6)

  auto stage = [&](int buf, int k0) {
#pragma unroll
    for (int i = 0; i < ASEG / 4; i++) {
      const int s = i * 4 + wave;
      const u16* gp = A + (size_t)(m0 + s * 8 + srow) * K + k0 + scol * 8;
      gload_lds16(gp, (char*)As[buf] + s * 1024 + lane * 16);
    }
#pragma unroll
    for (int i = 0; i < BSEG / 4; i++) {
      const int s = i * 4 + wave;
      const u16* gp = Bt + (size_t)(n0 + s * 8 + srow) * K + k0 + scol * 8;
      gload_lds16(gp, (char*)Bs[buf] + s * 1024 + lane * 16);
    }
  };

  auto compute = [&](int buf) {
#pragma unroll
    for (int kk = 0; kk < BK; kk += 32) {
      bf16x8 av[FM], bv[FN];
      const int cg = (kk >> 3) + g;
#pragma unroll
      for (int i = 0; i < FM; i++) {
        const int row = wr * (BM / 2) + i * 16 + r;
        av[i] = *reinterpret_cast<const bf16x8*>(
            &As[buf][row * 64 + ((cg ^ (row & 7)) << 3)]);
      }
#pragma unroll
      for (int j = 0; j < FN; j++) {
        const int row = wc * (BN / 2) + j * 16 + r;
        bv[j] = *reinterpret_cast<const bf16x8*>(
            &Bs[buf][row * 64 + ((cg ^ (row & 7)) << 3)]);
      }
      __builtin_amdgcn_s_setprio(1);
#pragma unroll
      for (int i = 0; i < FM; i++)
#pragma unroll
        for (int j = 0; j < FN; j++)
          acc[i][j] = __builtin_amdgcn_mfma_f32_16x16x32_bf16(av[i], bv[j], acc[i][j], 0, 0, 0);
      __builtin_amdgcn_s_setprio(0);
    }
  };

  const int NT = K >> 6;   // >= 8 for all our shapes
  stage(0, 0);
  stage(1, 64);
  asm volatile("s_waitcnt vmcnt(6)" ::: "memory");  // tile0 landed, tile1 in flight
  __builtin_amdgcn_s_barrier();
  __builtin_amdgcn_sched_barrier(0);
  for (int t = 0; t < NT - 2; ++t) {
    stage((t + 2) % 3, (t + 2) << 6);
    compute(t % 3);
    asm volatile("s_waitcnt vmcnt(6)" ::: "memory");  // tile t+1 landed, t+2 in flight
    __builtin_amdgcn_s_barrier();
    __builtin_amdgcn_sched_barrier(0);
  }
  compute((NT - 2) % 3);
  asm volatile("s_waitcnt vmcnt(0)" ::: "memory");
  __builtin_amdgcn_s_barrier();
  __builtin_amdgcn_sched_barrier(0);
  compute((NT - 1) % 3);

#pragma unroll
  for (int i = 0; i < FM; i++) {
#pragma unroll
    for (int j = 0; j < FN; j++) {
      const int col = n0 + wc * (BN / 2) + j * 16 + r;
      const float bc = BIAS ? bias[col] : 0.f;
#pragma unroll
      for (int rr = 0; rr < 4; rr++) {
        const int row = m0 + wr * (BM / 2) + i * 16 + g * 4 + rr;
        float v = acc[i][j][rr] + bc;
        if (RELU) v = fmaxf(v, 0.f);
        if (RESID) v += resid[(size_t)row * N + col];
        if (OUTBF) ((u16*)outp)[(size_t)row * N + col] = f2bf(v);
        else       ((float*)outp)[(size_t)row * N + col] = v;
      }
    }
  }
}

// ---------------------------------------------------------------------------
// MFMA sliding-window attention (unchanged from R3).
// ---------------------------------------------------------------------------
__global__ __launch_bounds__(256) void attn_kernel(
    const u16* __restrict__ qkv, const int* __restrict__ mask,
    u16* __restrict__ out) {
  __shared__ __align__(16) u16 Vt[64][128];
  __shared__ __align__(16) u16 Pl[4][16][72];
  __shared__ int ml[96];
  const int b = blockIdx.y >> 3, h = blockIdx.y & 7;
  const int t0 = blockIdx.x * 64;
  const int tid = threadIdx.x;
  const int wave = tid >> 6, lane = tid & 63;
  const int q15 = lane & 15, g = lane >> 4;

  for (int s = tid; s < 112 * 8; s += 256) {
    const int c = s >> 3, seg = s & 7;
    u16x8 v8 = {0, 0, 0, 0, 0, 0, 0, 0};
    const int kt = t0 - 16 + c;
    if (c < 96 && kt >= 0 && kt < T_SEQ)
      v8 = *(const u16x8*)(qkv + (size_t)(b * T_SEQ + kt) * 1536 + 1024 + h * 64 + seg * 8);
#pragma unroll
    for (int j = 0; j < 8; j++) {
      const int d = seg * 8 + j;
      const int cp = (c & 7) | ((((c >> 3) ^ seg) & 15) << 3);
      Vt[d][cp] = v8[j];
    }
  }
  for (int i = tid; i < 96; i += 256) {
    const int kt = t0 - 16 + i;
    ml[i] = (kt >= 0 && kt < T_SEQ) ? mask[b * T_SEQ + kt] : 0;
  }

  const size_t qrow = (size_t)(b * T_SEQ + t0 + wave * 16 + q15) * 1536 + h * 64;
  bf16x8 qf[2];
  qf[0] = *(const bf16x8*)(qkv + qrow + g * 8);
  qf[1] = *(const bf16x8*)(qkv + qrow + 32 + g * 8);
  bf16x8 kf[3][2];
#pragma unroll
  for (int mt = 0; mt < 3; mt++) {
    int kt = t0 - 16 + wave * 16 + mt * 16 + q15;
    kt = kt < 0 ? 0 : (kt >= T_SEQ ? T_SEQ - 1 : kt);
    const size_t kr = (size_t)(b * T_SEQ + kt) * 1536 + 512 + h * 64;
    kf[mt][0] = *(const bf16x8*)(qkv + kr + g * 8);
    kf[mt][1] = *(const bf16x8*)(qkv + kr + 32 + g * 8);
  }

  f32x4 sa[3];
#pragma unroll
  for (int mt = 0; mt < 3; mt++) sa[mt] = (f32x4){0.f, 0.f, 0.f, 0.f};
#pragma unroll
  for (int ks = 0; ks < 2; ks++)
#pragma unroll
    for (int mt = 0; mt < 3; mt++)
      sa[mt] = __builtin_amdgcn_mfma_f32_16x16x32_bf16(kf[mt][ks], qf[ks], sa[mt], 0, 0, 0);

  __syncthreads();

  float p[12];
  float mx = -1e30f;
#pragma unroll
  for (int mt = 0; mt < 3; mt++)
#pragma unroll
    for (int rr = 0; rr < 4; rr++) {
      const int cl = mt * 16 + g * 4 + rr;
      const bool ok = (cl >= q15) && (cl <= q15 + 32) && (ml[wave * 16 + cl] != 0);
      const float s = ok ? sa[mt][rr] * 0.125f : -1e9f;
      p[mt * 4 + rr] = s;
      mx = fmaxf(mx, s);
    }
  mx = fmaxf(mx, __shfl_xor(mx, 16));
  mx = fmaxf(mx, __shfl_xor(mx, 32));
  float sum = 0.f;
#pragma unroll
  for (int i = 0; i < 12; i++) { p[i] = __expf(p[i] - mx); sum += p[i]; }
  sum += __shfl_xor(sum, 16);
  sum += __shfl_xor(sum, 32);
  const float inv = 1.f / sum;

  u16* prow = &Pl[wave][q15][0];
#pragma unroll
  for (int mt = 0; mt < 3; mt++) {
    const u32 w0 = (u32)f2bf(p[mt * 4 + 0] * inv) | ((u32)f2bf(p[mt * 4 + 1] * inv) << 16);
    const u32 w1 = (u32)f2bf(p[mt * 4 + 2] * inv) | ((u32)f2bf(p[mt * 4 + 3] * inv) << 16);
    *(u32*)(prow + mt * 16 + g * 4) = w0;
    *(u32*)(prow + mt * 16 + g * 4 + 2) = w1;
  }
  *(u32*)(prow + 48 + g * 4) = 0;
  *(u32*)(prow + 48 + g * 4 + 2) = 0;

  f32x4 oa[4];
#pragma unroll
  for (int nt = 0; nt < 4; nt++) oa[nt] = (f32x4){0.f, 0.f, 0.f, 0.f};
#pragma unroll
  for (int ks = 0; ks < 2; ks++) {
    const bf16x8 pa = *(const bf16x8*)(&Pl[wave][q15][ks * 32 + g * 8]);
#pragma unroll
    for (int nt = 0; nt < 4; nt++) {
      const int d = nt * 16 + q15;
      const int chunk = 2 * wave + 4 * ks + g;
      const int cp = ((chunk ^ ((d >> 3) & 7)) & 15) << 3;
      const bf16x8 vb = *(const bf16x8*)(&Vt[d][cp]);
      oa[nt] = __builtin_amdgcn_mfma_f32_16x16x32_bf16(pa, vb, oa[nt], 0, 0, 0);
    }
  }

  u16* orow = out + (size_t)(b * T_SEQ + t0 + wave * 16) * E_DIM + h * 64;
#pragma unroll
  for (int nt = 0; nt < 4; nt++)
#pragma unroll
    for (int rr = 0; rr < 4; rr++)
      orow[(size_t)(g * 4 + rr) * E_DIM + nt * 16 + q15] = f2bf(oa[nt][rr]);
}

// ---------------------------------------------------------------------------
extern "C" void kernel_launch(void* const* d_in, const int* in_sizes, int n_in,
                              void* d_out, int out_size, void* d_ws, size_t ws_size,
                              hipStream_t stream) {
  const int*   tokens   = (const int*)d_in[0];
  const int*   attnmask = (const int*)d_in[1];
  const float* tok_emb  = (const float*)d_in[2];
  const float* pos_emb  = (const float*)d_in[3];
  const float* Wq       = (const float*)d_in[4];
  const float* Wk       = (const float*)d_in[5];
  const float* Wv       = (const float*)d_in[6];
  const float* Wo       = (const float*)d_in[7];
  const float* bo       = (const float*)d_in[8];
  const float* ln1_g    = (const float*)d_in[9];
  const float* ln1_b    = (const float*)d_in[10];
  const float* ln2_g    = (const float*)d_in[11];
  const float* ln2_b    = (const float*)d_in[12];
  const float* W1       = (const float*)d_in[13];
  const float* b1       = (const float*)d_in[14];
  const float* W2       = (const float*)d_in[15];
  const float* b2       = (const float*)d_in[16];
  float* x = (float*)d_out;  // residual stream lives in d_out (fp32)

  u16* wqkv_t  = (u16*)d_ws;                      // 2*1536*512
  u16* wo_t    = wqkv_t + 2 * 1536 * 512;         // 2*512*512
  u16* w1_t    = wo_t + 2 * 512 * 512;            // 2*2048*512
  u16* w2_t    = w1_t + 2 * 2048 * 512;           // 2*512*2048
  u16* h_bf    = w2_t + 2 * 512 * 2048;           // 8192*512
  u16* qkv_bf  = h_bf + (size_t)MROWS * 512;      // 8192*1536
  u16* attn_bf = qkv_bf + (size_t)MROWS * 1536;   // 8192*512
  u16* mid_bf  = attn_bf + (size_t)MROWS * 512;   // 8192*2048

  wconv_kernel<<<dim3(1024, 12), 256, 0, stream>>>(Wq, Wk, Wv, Wo, W1, W2,
                                                   wqkv_t, wo_t, w1_t, w2_t);
  embed_kernel<<<dim3(4096), 256, 0, stream>>>(tokens, tok_emb, pos_emb, x);

  for (int l = 0; l < 2; l++) {
    const size_t EE = (size_t)512 * 512;
    const size_t EF = (size_t)512 * 2048;
    ln_kernel<<<dim3(2048), 256, 0, stream>>>(x, ln1_g + l * 512, ln1_b + l * 512, h_bf);
    // QKV: [8192,512] @ [512,1536]^T  grid 24x64 = 1536
    gemm_nt<128, 64, false, false, false, true>
        <<<dim3(1536), 256, 0, stream>>>(h_bf, wqkv_t + l * 3 * EE,
                                         nullptr, nullptr, qkv_bf, 512, 1536, 24);
    attn_kernel<<<dim3(64, 16), 256, 0, stream>>>(qkv_bf, attnmask, attn_bf);
    // Wo: x += attn @ Wo + bo   grid 8x64 = 512
    gemm_nt<128, 64, true, false, true, false>
        <<<dim3(512), 256, 0, stream>>>(attn_bf, wo_t + l * EE,
                                        bo + l * 512, x, x, 512, 512, 8);
    ln_kernel<<<dim3(2048), 256, 0, stream>>>(x, ln2_g + l * 512, ln2_b + l * 512, h_bf);
    // FFN1: relu(h @ W1 + b1) -> mid_bf   grid 32x64 = 2048
    gemm_nt<128, 64, true, true, false, true>
        <<<dim3(2048), 256, 0, stream>>>(h_bf, w1_t + l * EF,
                                         b1 + l * 2048, nullptr, mid_bf, 512, 2048, 32);
    // FFN2: x += mid @ W2 + b2   grid 8x64 = 512
    gemm_nt<128, 64, true, false, true, false>
        <<<dim3(512), 256, 0, stream>>>(mid_bf, w2_t + l * EF,
                                        b2 + l * 512, x, x, 2048, 512, 8);
  }
}

// Round 6
// 373.732 us; speedup vs baseline: 1.0884x; 1.0884x over previous
//
#include <hip/hip_runtime.h>

typedef unsigned short u16;
typedef unsigned int u32;
typedef __bf16 bf16x8 __attribute__((ext_vector_type(8)));
typedef float f32x4 __attribute__((ext_vector_type(4)));
typedef u16 u16x8 __attribute__((ext_vector_type(8)));

#define T_SEQ 4096
#define E_DIM 512
#define H_HEADS 8
#define FF_DIM 2048
#define BATCH 2
#define MROWS (BATCH * T_SEQ) /* 8192 */

__device__ __forceinline__ float bf2f(u16 u) {
  union { u32 i; float f; } w; w.i = ((u32)u) << 16; return w.f;
}
__device__ __forceinline__ u16 f2bf(float f) {
  union { float f; u32 i; } w; w.f = f;
  u32 r = w.i + 0x7FFFu + ((w.i >> 16) & 1u);
  return (u16)(r >> 16);
}
__device__ __forceinline__ void gload_lds16(const void* g, void* l) {
  __builtin_amdgcn_global_load_lds(
      (const __attribute__((address_space(1))) void*)g,
      (__attribute__((address_space(3))) void*)l, 16, 0, 0);
}

// ---------------------------------------------------------------------------
// Weight convert+transpose: out[n][k] = (bf16) in[k][n]
// ---------------------------------------------------------------------------
__global__ __launch_bounds__(256) void wconv_kernel(
    const float* __restrict__ Wq, const float* __restrict__ Wk,
    const float* __restrict__ Wv, const float* __restrict__ Wo,
    const float* __restrict__ W1, const float* __restrict__ W2,
    u16* __restrict__ wqkv_t, u16* __restrict__ wo_t,
    u16* __restrict__ w1_t, u16* __restrict__ w2_t) {
  const int z = blockIdx.y;
  const int l = z / 6, ty = z % 6;
  const float* in; u16* op; int K, N;
  const size_t EE = (size_t)E_DIM * E_DIM;
  const size_t EF = (size_t)E_DIM * FF_DIM;
  switch (ty) {
    case 0: in = Wq + l * EE; op = wqkv_t + l * 3 * EE;          K = E_DIM;  N = E_DIM;  break;
    case 1: in = Wk + l * EE; op = wqkv_t + l * 3 * EE + EE;     K = E_DIM;  N = E_DIM;  break;
    case 2: in = Wv + l * EE; op = wqkv_t + l * 3 * EE + 2 * EE; K = E_DIM;  N = E_DIM;  break;
    case 3: in = Wo + l * EE; op = wo_t + l * EE;                K = E_DIM;  N = E_DIM;  break;
    case 4: in = W1 + l * EF; op = w1_t + l * EF;                K = E_DIM;  N = FF_DIM; break;
    default:in = W2 + l * EF; op = w2_t + l * EF;                K = FF_DIM; N = E_DIM;  break;
  }
  const int nn = N >> 5;
  const int ntile = (K >> 5) * nn;
  const int tile = blockIdx.x;
  if (tile >= ntile) return;
  const int tk = tile / nn, tn = tile % nn;
  __shared__ float tl[32][33];
  const int tx = threadIdx.x & 31, tr = threadIdx.x >> 5;
#pragma unroll
  for (int i = 0; i < 4; i++)
    tl[tr + i * 8][tx] = in[(size_t)(tk * 32 + tr + i * 8) * N + tn * 32 + tx];
  __syncthreads();
#pragma unroll
  for (int i = 0; i < 4; i++)
    op[(size_t)(tn * 32 + tr + i * 8) * K + tk * 32 + tx] = f2bf(tl[tx][tr + i * 8]);
}

// ---------------------------------------------------------------------------
// Embedding
// ---------------------------------------------------------------------------
__global__ __launch_bounds__(256) void embed_kernel(
    const int* __restrict__ tokens, const float* __restrict__ tok_emb,
    const float* __restrict__ pos_emb, float* __restrict__ x) {
  const int idx = blockIdx.x * 256 + threadIdx.x;   // over 8192*128
  const int rowi = idx >> 7, c4 = (idx & 127) * 4;
  const int t = rowi & (T_SEQ - 1);
  const int tok = tokens[rowi];
  float4 e = *(const float4*)(tok_emb + (size_t)tok * E_DIM + c4);
  float4 p = *(const float4*)(pos_emb + (size_t)t * E_DIM + c4);
  e.x += p.x; e.y += p.y; e.z += p.z; e.w += p.w;
  *(float4*)(x + (size_t)rowi * E_DIM + c4) = e;
}

// ---------------------------------------------------------------------------
// LayerNorm: one wave per row of 512; fp32 in, bf16 out.
// ---------------------------------------------------------------------------
__global__ __launch_bounds__(256) void ln_kernel(
    const float* __restrict__ x, const float* __restrict__ gam,
    const float* __restrict__ bet, u16* __restrict__ out) {
  const int row = blockIdx.x * 4 + (threadIdx.x >> 6);
  const int lane = threadIdx.x & 63;
  const float* xr = x + (size_t)row * E_DIM + lane * 8;
  float4 v0 = *(const float4*)xr;
  float4 v1 = *(const float4*)(xr + 4);
  float s  = v0.x + v0.y + v0.z + v0.w + v1.x + v1.y + v1.z + v1.w;
  float s2 = v0.x * v0.x + v0.y * v0.y + v0.z * v0.z + v0.w * v0.w +
             v1.x * v1.x + v1.y * v1.y + v1.z * v1.z + v1.w * v1.w;
#pragma unroll
  for (int o = 32; o; o >>= 1) { s += __shfl_xor(s, o); s2 += __shfl_xor(s2, o); }
  const float mean = s * (1.f / E_DIM);
  const float var = s2 * (1.f / E_DIM) - mean * mean;
  const float inv = rsqrtf(var + 1e-5f);
  float4 g0 = *(const float4*)(gam + lane * 8);
  float4 g1 = *(const float4*)(gam + lane * 8 + 4);
  float4 b0 = *(const float4*)(bet + lane * 8);
  float4 b1 = *(const float4*)(bet + lane * 8 + 4);
  u16x8 o8;
  o8[0] = f2bf((v0.x - mean) * inv * g0.x + b0.x);
  o8[1] = f2bf((v0.y - mean) * inv * g0.y + b0.y);
  o8[2] = f2bf((v0.z - mean) * inv * g0.z + b0.z);
  o8[3] = f2bf((v0.w - mean) * inv * g0.w + b0.w);
  o8[4] = f2bf((v1.x - mean) * inv * g1.x + b1.x);
  o8[5] = f2bf((v1.y - mean) * inv * g1.y + b1.y);
  o8[6] = f2bf((v1.z - mean) * inv * g1.z + b1.z);
  o8[7] = f2bf((v1.w - mean) * inv * g1.w + b1.w);
  *(u16x8*)(out + (size_t)row * E_DIM + lane * 8) = o8;
}

// ---------------------------------------------------------------------------
// NT GEMM: C[M,N] = A[M,K] @ Bt[N,K]^T, bf16 in, fp32 acc.
// m97-proven structure: SINGLE-buffer LDS, 2-barrier serial K-loop
// (sync; stage; sync; compute). Small LDS (32KB at 128x128, 24KB at 64x128)
// -> 4-6 resident blocks/CU; inter-block wave overlap (m114) hides the
// stage+vmcnt-drain stall that intra-block pipelining couldn't (R5 lesson:
// 3-buf 72KB capped residency at 2 blocks/CU and regressed).
// T2 both-sides XOR swizzle (conflict-free), T1 XCD swizzle, T5 setprio.
// Block 256 (4 waves, 2x2). grid: 1-D, gx = N/BN tiles.
// ---------------------------------------------------------------------------
template <int BM, int BN, bool BIAS, bool RELU, bool RESID, bool OUTBF>
__global__ __launch_bounds__(256) void gemm_nt(
    const u16* __restrict__ A, const u16* __restrict__ Bt,
    const float* __restrict__ bias, const float* __restrict__ resid,
    void* __restrict__ outp, int K, int N, int gx) {
  constexpr int BK = 64;
  constexpr int FM = BM / 32, FN = BN / 32;
  __shared__ __align__(16) u16 As[BM * BK];
  __shared__ __align__(16) u16 Bs[BN * BK];
  const int tid = threadIdx.x;
  const int wave = tid >> 6, lane = tid & 63;

  // T1: bijective XCD swizzle (grid always a multiple of 8)
  const int cpx = gridDim.x >> 3;
  const int bid = blockIdx.x;
  const int sw = (bid & 7) * cpx + (bid >> 3);
  const int bx = sw % gx, by = sw / gx;

  const int m0 = by * BM, n0 = bx * BN;
  const int wr = wave >> 1, wc = wave & 1;
  const int r = lane & 15, g = lane >> 4;

  // staging source swizzle (T2 both-sides, rule 21)
  const int srow = lane >> 3;
  const int scol = (lane & 7) ^ srow;

  f32x4 acc[FM][FN];
#pragma unroll
  for (int i = 0; i < FM; i++)
#pragma unroll
    for (int j = 0; j < FN; j++) acc[i][j] = (f32x4){0.f, 0.f, 0.f, 0.f};

  constexpr int ASEG = BM / 8, BSEG = BN / 8;

  for (int k0 = 0; k0 < K; k0 += BK) {
    __syncthreads();   // previous compute done reading LDS
#pragma unroll
    for (int i = 0; i < ASEG / 4; i++) {
      const int s = i * 4 + wave;
      const u16* gp = A + (size_t)(m0 + s * 8 + srow) * K + k0 + scol * 8;
      gload_lds16(gp, (char*)As + s * 1024 + lane * 16);
    }
#pragma unroll
    for (int i = 0; i < BSEG / 4; i++) {
      const int s = i * 4 + wave;
      const u16* gp = Bt + (size_t)(n0 + s * 8 + srow) * K + k0 + scol * 8;
      gload_lds16(gp, (char*)Bs + s * 1024 + lane * 16);
    }
    __syncthreads();   // implies vmcnt(0) drain: tile staged
#pragma unroll
    for (int kk = 0; kk < BK; kk += 32) {
      bf16x8 av[FM], bv[FN];
      const int cg = (kk >> 3) + g;
#pragma unroll
      for (int i = 0; i < FM; i++) {
        const int row = wr * (BM / 2) + i * 16 + r;
        av[i] = *reinterpret_cast<const bf16x8*>(
            &As[row * 64 + ((cg ^ (row & 7)) << 3)]);
      }
#pragma unroll
      for (int j = 0; j < FN; j++) {
        const int row = wc * (BN / 2) + j * 16 + r;
        bv[j] = *reinterpret_cast<const bf16x8*>(
            &Bs[row * 64 + ((cg ^ (row & 7)) << 3)]);
      }
      __builtin_amdgcn_s_setprio(1);
#pragma unroll
      for (int i = 0; i < FM; i++)
#pragma unroll
        for (int j = 0; j < FN; j++)
          acc[i][j] = __builtin_amdgcn_mfma_f32_16x16x32_bf16(av[i], bv[j], acc[i][j], 0, 0, 0);
      __builtin_amdgcn_s_setprio(0);
    }
  }

#pragma unroll
  for (int i = 0; i < FM; i++) {
#pragma unroll
    for (int j = 0; j < FN; j++) {
      const int col = n0 + wc * (BN / 2) + j * 16 + r;
      const float bc = BIAS ? bias[col] : 0.f;
#pragma unroll
      for (int rr = 0; rr < 4; rr++) {
        const int row = m0 + wr * (BM / 2) + i * 16 + g * 4 + rr;
        float v = acc[i][j][rr] + bc;
        if (RELU) v = fmaxf(v, 0.f);
        if (RESID) v += resid[(size_t)row * N + col];
        if (OUTBF) ((u16*)outp)[(size_t)row * N + col] = f2bf(v);
        else       ((float*)outp)[(size_t)row * N + col] = v;
      }
    }
  }
}

// ---------------------------------------------------------------------------
// MFMA sliding-window attention (unchanged from R3).
// ---------------------------------------------------------------------------
__global__ __launch_bounds__(256) void attn_kernel(
    const u16* __restrict__ qkv, const int* __restrict__ mask,
    u16* __restrict__ out) {
  __shared__ __align__(16) u16 Vt[64][128];
  __shared__ __align__(16) u16 Pl[4][16][72];
  __shared__ int ml[96];
  const int b = blockIdx.y >> 3, h = blockIdx.y & 7;
  const int t0 = blockIdx.x * 64;
  const int tid = threadIdx.x;
  const int wave = tid >> 6, lane = tid & 63;
  const int q15 = lane & 15, g = lane >> 4;

  for (int s = tid; s < 112 * 8; s += 256) {
    const int c = s >> 3, seg = s & 7;
    u16x8 v8 = {0, 0, 0, 0, 0, 0, 0, 0};
    const int kt = t0 - 16 + c;
    if (c < 96 && kt >= 0 && kt < T_SEQ)
      v8 = *(const u16x8*)(qkv + (size_t)(b * T_SEQ + kt) * 1536 + 1024 + h * 64 + seg * 8);
#pragma unroll
    for (int j = 0; j < 8; j++) {
      const int d = seg * 8 + j;
      const int cp = (c & 7) | ((((c >> 3) ^ seg) & 15) << 3);
      Vt[d][cp] = v8[j];
    }
  }
  for (int i = tid; i < 96; i += 256) {
    const int kt = t0 - 16 + i;
    ml[i] = (kt >= 0 && kt < T_SEQ) ? mask[b * T_SEQ + kt] : 0;
  }

  const size_t qrow = (size_t)(b * T_SEQ + t0 + wave * 16 + q15) * 1536 + h * 64;
  bf16x8 qf[2];
  qf[0] = *(const bf16x8*)(qkv + qrow + g * 8);
  qf[1] = *(const bf16x8*)(qkv + qrow + 32 + g * 8);
  bf16x8 kf[3][2];
#pragma unroll
  for (int mt = 0; mt < 3; mt++) {
    int kt = t0 - 16 + wave * 16 + mt * 16 + q15;
    kt = kt < 0 ? 0 : (kt >= T_SEQ ? T_SEQ - 1 : kt);
    const size_t kr = (size_t)(b * T_SEQ + kt) * 1536 + 512 + h * 64;
    kf[mt][0] = *(const bf16x8*)(qkv + kr + g * 8);
    kf[mt][1] = *(const bf16x8*)(qkv + kr + 32 + g * 8);
  }

  f32x4 sa[3];
#pragma unroll
  for (int mt = 0; mt < 3; mt++) sa[mt] = (f32x4){0.f, 0.f, 0.f, 0.f};
#pragma unroll
  for (int ks = 0; ks < 2; ks++)
#pragma unroll
    for (int mt = 0; mt < 3; mt++)
      sa[mt] = __builtin_amdgcn_mfma_f32_16x16x32_bf16(kf[mt][ks], qf[ks], sa[mt], 0, 0, 0);

  __syncthreads();

  float p[12];
  float mx = -1e30f;
#pragma unroll
  for (int mt = 0; mt < 3; mt++)
#pragma unroll
    for (int rr = 0; rr < 4; rr++) {
      const int cl = mt * 16 + g * 4 + rr;
      const bool ok = (cl >= q15) && (cl <= q15 + 32) && (ml[wave * 16 + cl] != 0);
      const float s = ok ? sa[mt][rr] * 0.125f : -1e9f;
      p[mt * 4 + rr] = s;
      mx = fmaxf(mx, s);
    }
  mx = fmaxf(mx, __shfl_xor(mx, 16));
  mx = fmaxf(mx, __shfl_xor(mx, 32));
  float sum = 0.f;
#pragma unroll
  for (int i = 0; i < 12; i++) { p[i] = __expf(p[i] - mx); sum += p[i]; }
  sum += __shfl_xor(sum, 16);
  sum += __shfl_xor(sum, 32);
  const float inv = 1.f / sum;

  u16* prow = &Pl[wave][q15][0];
#pragma unroll
  for (int mt = 0; mt < 3; mt++) {
    const u32 w0 = (u32)f2bf(p[mt * 4 + 0] * inv) | ((u32)f2bf(p[mt * 4 + 1] * inv) << 16);
    const u32 w1 = (u32)f2bf(p[mt * 4 + 2] * inv) | ((u32)f2bf(p[mt * 4 + 3] * inv) << 16);
    *(u32*)(prow + mt * 16 + g * 4) = w0;
    *(u32*)(prow + mt * 16 + g * 4 + 2) = w1;
  }
  *(u32*)(prow + 48 + g * 4) = 0;
  *(u32*)(prow + 48 + g * 4 + 2) = 0;

  f32x4 oa[4];
#pragma unroll
  for (int nt = 0; nt < 4; nt++) oa[nt] = (f32x4){0.f, 0.f, 0.f, 0.f};
#pragma unroll
  for (int ks = 0; ks < 2; ks++) {
    const bf16x8 pa = *(const bf16x8*)(&Pl[wave][q15][ks * 32 + g * 8]);
#pragma unroll
    for (int nt = 0; nt < 4; nt++) {
      const int d = nt * 16 + q15;
      const int chunk = 2 * wave + 4 * ks + g;
      const int cp = ((chunk ^ ((d >> 3) & 7)) & 15) << 3;
      const bf16x8 vb = *(const bf16x8*)(&Vt[d][cp]);
      oa[nt] = __builtin_amdgcn_mfma_f32_16x16x32_bf16(pa, vb, oa[nt], 0, 0, 0);
    }
  }

  u16* orow = out + (size_t)(b * T_SEQ + t0 + wave * 16) * E_DIM + h * 64;
#pragma unroll
  for (int nt = 0; nt < 4; nt++)
#pragma unroll
    for (int rr = 0; rr < 4; rr++)
      orow[(size_t)(g * 4 + rr) * E_DIM + nt * 16 + q15] = f2bf(oa[nt][rr]);
}

// ---------------------------------------------------------------------------
extern "C" void kernel_launch(void* const* d_in, const int* in_sizes, int n_in,
                              void* d_out, int out_size, void* d_ws, size_t ws_size,
                              hipStream_t stream) {
  const int*   tokens   = (const int*)d_in[0];
  const int*   attnmask = (const int*)d_in[1];
  const float* tok_emb  = (const float*)d_in[2];
  const float* pos_emb  = (const float*)d_in[3];
  const float* Wq       = (const float*)d_in[4];
  const float* Wk       = (const float*)d_in[5];
  const float* Wv       = (const float*)d_in[6];
  const float* Wo       = (const float*)d_in[7];
  const float* bo       = (const float*)d_in[8];
  const float* ln1_g    = (const float*)d_in[9];
  const float* ln1_b    = (const float*)d_in[10];
  const float* ln2_g    = (const float*)d_in[11];
  const float* ln2_b    = (const float*)d_in[12];
  const float* W1       = (const float*)d_in[13];
  const float* b1       = (const float*)d_in[14];
  const float* W2       = (const float*)d_in[15];
  const float* b2       = (const float*)d_in[16];
  float* x = (float*)d_out;  // residual stream lives in d_out (fp32)

  u16* wqkv_t  = (u16*)d_ws;                      // 2*1536*512
  u16* wo_t    = wqkv_t + 2 * 1536 * 512;         // 2*512*512
  u16* w1_t    = wo_t + 2 * 512 * 512;            // 2*2048*512
  u16* w2_t    = w1_t + 2 * 2048 * 512;           // 2*512*2048
  u16* h_bf    = w2_t + 2 * 512 * 2048;           // 8192*512
  u16* qkv_bf  = h_bf + (size_t)MROWS * 512;      // 8192*1536
  u16* attn_bf = qkv_bf + (size_t)MROWS * 1536;   // 8192*512
  u16* mid_bf  = attn_bf + (size_t)MROWS * 512;   // 8192*2048

  wconv_kernel<<<dim3(1024, 12), 256, 0, stream>>>(Wq, Wk, Wv, Wo, W1, W2,
                                                   wqkv_t, wo_t, w1_t, w2_t);
  embed_kernel<<<dim3(4096), 256, 0, stream>>>(tokens, tok_emb, pos_emb, x);

  for (int l = 0; l < 2; l++) {
    const size_t EE = (size_t)512 * 512;
    const size_t EF = (size_t)512 * 2048;
    ln_kernel<<<dim3(2048), 256, 0, stream>>>(x, ln1_g + l * 512, ln1_b + l * 512, h_bf);
    // QKV: [8192,512] @ [512,1536]^T  grid 12x64 = 768  (128x128, 32KB LDS)
    gemm_nt<128, 128, false, false, false, true>
        <<<dim3(768), 256, 0, stream>>>(h_bf, wqkv_t + l * 3 * EE,
                                        nullptr, nullptr, qkv_bf, 512, 1536, 12);
    attn_kernel<<<dim3(64, 16), 256, 0, stream>>>(qkv_bf, attnmask, attn_bf);
    // Wo: x += attn @ Wo + bo   grid 4x128 = 512  (64x128, 24KB LDS)
    gemm_nt<64, 128, true, false, true, false>
        <<<dim3(512), 256, 0, stream>>>(attn_bf, wo_t + l * EE,
                                        bo + l * 512, x, x, 512, 512, 4);
    ln_kernel<<<dim3(2048), 256, 0, stream>>>(x, ln2_g + l * 512, ln2_b + l * 512, h_bf);
    // FFN1: relu(h @ W1 + b1) -> mid_bf   grid 16x64 = 1024  (128x128)
    gemm_nt<128, 128, true, true, false, true>
        <<<dim3(1024), 256, 0, stream>>>(h_bf, w1_t + l * EF,
                                         b1 + l * 2048, nullptr, mid_bf, 512, 2048, 16);
    // FFN2: x += mid @ W2 + b2   grid 4x128 = 512  (64x128)
    gemm_nt<64, 128, true, false, true, false>
        <<<dim3(512), 256, 0, stream>>>(mid_bf, w2_t + l * EF,
                                        b2 + l * 512, x, x, 2048, 512, 4);
  }
}